// Round 10
// baseline (2570.892 us; speedup 1.0000x reference)
//
#include <hip/hip_runtime.h>

#define HID 15
#define NG  60      // 4*HID
#define DIM 64
#define T2  2048
#define NLAY 4
#define BSZ 512

// bf16 RNE rounding — PROVEN bit-trick (rounds 6/7). The v_cvt_pk_bf16_f32
// shortcut produced NaNs twice (even battery-guarded) — do not revisit.
__device__ __forceinline__ float bfr(float x) {
    unsigned u = __float_as_uint(x);
    u = (u + 0x7FFFu + ((u >> 16) & 1u)) & 0xFFFF0000u;
    return __uint_as_float(u);
}
// one bf16-rounded multiply-accumulate term: acc = bf(acc + bf(a*b))
#define CH(acc, a, b) acc = bfr(acc + bfr((a) * (b)))

__device__ __forceinline__ float tanh_np(float z) {
    const float e = __expf(-2.0f * z);
    return bfr((1.0f - e) / (1.0f + e));
}
__device__ __forceinline__ float sig_np(float z) {
    const float e   = bfr(__expf(-z));
    const float den = bfr(1.0f + e);
    return bfr(1.0f / den);
}
__device__ __forceinline__ float b2f(unsigned short b) {
    return __uint_as_float(((unsigned)b) << 16);
}

// ============ Phase 1: layer-0 input projection (round-7 exact) ============
// Issue-bound at 8 waves/SIMD (~450us); no point pipelining further.
__global__ __launch_bounds__(256, 1)
void proj0(const float* __restrict__ emb,
           const int*   __restrict__ lengths,
           const float* __restrict__ Wih0,
           unsigned short* __restrict__ pa)
{
    const int wave = threadIdx.x >> 6;
    const int lane = threadIdx.x & 63;
    const int g    = (lane < NG) ? lane : (NG - 1);

    __shared__ __align__(16) float xrow[4][64];

    float wx[DIM];
    #pragma unroll
    for (int q = 0; q < 16; ++q) {
        float4 w = *(const float4*)(Wih0 + g*DIM + 4*q);
        wx[4*q+0] = bfr(w.x); wx[4*q+1] = bfr(w.y);
        wx[4*q+2] = bfr(w.z); wx[4*q+3] = bfr(w.w);
    }

    const int nrows = BSZ * T2;
    for (int r = blockIdx.x * 4 + wave; r < nrows; r += gridDim.x * 4) {
        const int b = r >> 11;          // r / T2
        const int t = r & (T2 - 1);
        if (t >= lengths[b]) continue;  // row never consumed by recurrence

        xrow[wave][lane] = bfr(emb[(size_t)r * DIM + lane]);
        const float4* xv = (const float4*)xrow[wave];
        float acc = 0.0f;
        #pragma unroll
        for (int q = 0; q < 16; ++q) {
            float4 v = xv[q];
            CH(acc, v.x, wx[4*q+0]);
            CH(acc, v.y, wx[4*q+1]);
            CH(acc, v.z, wx[4*q+2]);
            CH(acc, v.w, wx[4*q+3]);
        }
        if (lane < NG)
            pa[(size_t)r * NG + g] = (unsigned short)(__float_as_uint(acc) >> 16);
    }
}

// ====== Phase 2: layer-pipelined recurrence with helper-wave split ======
// Waves 0-3 ("main"): layer l = wave. Per superstep k, main l handles t=k-l:
//   phase A: a_rec chain (own h, SGPR-broadcast); wave0 also pa prefetch.
//   phase B (after mid-barrier): a_in from a_in_lds (or pa), z, activation,
//            cell, h write, SGPR re-broadcast.
// Waves 4-6 ("helper"): layer L = wave-3. Phase A: read h_{L-1}(t) from LDS
//   (written by main L-1 at superstep k-1), compute the a_in chain, publish
//   to a_in_lds[L]. Main L consumes it in phase B of the SAME superstep.
// Barriers: mid + end, every superstep, all 7 waves unconditionally.
// Op sequence per gate is identical to round 7 -> bit-identical output.
__global__ __launch_bounds__(448, 1)
void lstm4_pipe(const int* __restrict__ lengths,
                const unsigned short* __restrict__ pa,
                const float* __restrict__ Wihr,
                const float* __restrict__ Whh,
                const float* __restrict__ bih,
                const float* __restrict__ bhh,
                float* __restrict__ out)
{
    const int s    = blockIdx.x;
    const int wave = threadIdx.x >> 6;
    const int lane = threadIdx.x & 63;
    const int g    = (lane < NG) ? lane : (NG - 1);

    __shared__ __align__(16) float h_lds[2][NLAY][16];
    __shared__ __align__(16) float a_in_lds[NLAY][64];

    int len = lengths[s];
    len = len < 1 ? 1 : (len > T2 ? T2 : len);

    const bool tg = (lane >= 30 && lane < 45);

    if (wave < NLAY) {
        // ---------------- MAIN wave: layer l = wave ----------------
        const int l = wave;
        float wr[16];
        #pragma unroll
        for (int j = 0; j < HID; ++j) wr[j] = bfr(Whh[(l*NG + g)*HID + j]);
        wr[15] = 0.0f;
        const float bias_ = bfr(bfr(bih[l*NG + g]) + bfr(bhh[l*NG + g]));

        const unsigned short* pas = pa + (size_t)s * T2 * NG;

        float c_ = 0.0f;
        float hs[HID];
        #pragma unroll
        for (int j = 0; j < HID; ++j) hs[j] = 0.0f;

        unsigned short panb = 0;
        if (l == 0) panb = pas[g];             // a_in bits for t=0

        for (int k = 0; k < len + NLAY - 1; ++k) {
            const int t = k - l;
            const bool valid = (t >= 0) & (t < len);

            float a_rec = 0.0f, a_in0 = 0.0f;
            if (valid) {
                // phase A: recurrent chain off uniform h (no memory dep)
                #pragma unroll
                for (int j = 0; j < HID; ++j) CH(a_rec, hs[j], wr[j]);
                if (l == 0) {
                    a_in0 = b2f(panb);
                    if (t + 1 < len) panb = pas[(size_t)(t + 1) * NG + g];
                }
            }
            __syncthreads();                    // mid: helpers published a_in

            if (valid) {
                const float a_in = (l == 0) ? a_in0 : a_in_lds[l][g];
                const float z = bfr(bfr(a_in + a_rec) + bias_);
                const float a = tg ? tanh_np(z) : sig_np(z);

                const float fv = __shfl(a, (lane + 15) & 63);
                const float gv = __shfl(a, (lane + 30) & 63);
                const float ov = __shfl(a, (lane + 45) & 63);

                const float cn = bfr(bfr(fv * c_) + bfr(a * gv));
                c_ = cn;
                const float hn = bfr(ov * tanh_np(cn));

                #pragma unroll
                for (int j = 0; j < HID; ++j)
                    hs[j] = __uint_as_float(__builtin_amdgcn_readlane(__float_as_uint(hn), j));

                if (lane < HID) h_lds[t & 1][l][lane] = hn;
                if (l == NLAY - 1 && t == len - 1 && lane < HID)
                    out[s * HID + lane] = hn;
            }
            __syncthreads();                    // end of superstep
        }
    } else {
        // ---------------- HELPER wave: a_in chain for layer L ----------------
        const int L = wave - 3;                 // waves 4,5,6 -> layers 1,2,3
        float wi[16];
        #pragma unroll
        for (int j = 0; j < HID; ++j) wi[j] = bfr(Wihr[((L-1)*NG + g)*HID + j]);
        wi[15] = 0.0f;

        for (int k = 0; k < len + NLAY - 1; ++k) {
            const int t = k - L;
            const bool valid = (t >= 0) & (t < len);

            if (valid) {
                // h_{L-1}(t): written by main L-1 at superstep k-1 (phase B),
                // separated from this read by end-barrier(k-1).
                float hv[16];
                const float4* hp = (const float4*)h_lds[t & 1][L - 1];
                *(float4*)&hv[0]  = hp[0]; *(float4*)&hv[4]  = hp[1];
                *(float4*)&hv[8]  = hp[2]; *(float4*)&hv[12] = hp[3];

                float a_in = 0.0f;
                #pragma unroll
                for (int j = 0; j < HID; ++j) CH(a_in, hv[j], wi[j]);
                a_in_lds[L][lane] = a_in;       // consumed after mid-barrier
            }
            __syncthreads();                    // mid
            __syncthreads();                    // end
        }
    }
}

// ============ Fallback (round-6, passing): used if ws too small ============
__global__ __launch_bounds__(64, 1)
void lstm4_bf16np(const float* __restrict__ emb,
                  const int*   __restrict__ lengths,
                  const float* __restrict__ Wih0,
                  const float* __restrict__ Wihr,
                  const float* __restrict__ Whh,
                  const float* __restrict__ bih,
                  const float* __restrict__ bhh,
                  float* __restrict__ out)
{
    const int s    = blockIdx.x;
    const int lane = threadIdx.x;
    const int g    = (lane < NG) ? lane : (NG - 1);

    __shared__ __align__(16) float x_lds[DIM];
    __shared__ __align__(16) float h_lds[NLAY][16];

    float wx[DIM];
    #pragma unroll
    for (int q = 0; q < DIM/4; ++q) {
        float4 w = *(const float4*)(Wih0 + g*DIM + 4*q);
        wx[4*q+0] = bfr(w.x); wx[4*q+1] = bfr(w.y);
        wx[4*q+2] = bfr(w.z); wx[4*q+3] = bfr(w.w);
    }
    float wr[NLAY][16]; float wi[NLAY-1][16]; float bias[NLAY];
    #pragma unroll
    for (int l = 0; l < NLAY; ++l) {
        #pragma unroll
        for (int j = 0; j < HID; ++j) wr[l][j] = bfr(Whh[(l*NG + g)*HID + j]);
        wr[l][15] = 0.0f;
        bias[l] = bfr(bfr(bih[l*NG + g]) + bfr(bhh[l*NG + g]));
    }
    #pragma unroll
    for (int l = 0; l < NLAY-1; ++l) {
        #pragma unroll
        for (int j = 0; j < HID; ++j) wi[l][j] = bfr(Wihr[(l*NG + g)*HID + j]);
        wi[l][15] = 0.0f;
    }
    if (lane < 16) {
        #pragma unroll
        for (int l = 0; l < NLAY; ++l) h_lds[l][lane] = 0.0f;
    }
    float c[NLAY] = {0.0f, 0.0f, 0.0f, 0.0f};
    int len = lengths[s];
    len = len < 1 ? 1 : (len > T2 ? T2 : len);
    const float* xb = emb + (size_t)s * T2 * DIM;
    x_lds[lane] = bfr(xb[lane]);
    __syncthreads();
    const bool tg = (lane >= 30 && lane < 45);
    const float4* x4 = (const float4*)x_lds;
    float hout = 0.0f;
    for (int t = 0; t < len; ++t) {
        const int tn = (t + 1 < len) ? (t + 1) : t;
        const float xn = bfr(xb[(size_t)tn * DIM + lane]);
        #pragma unroll
        for (int l = 0; l < NLAY; ++l) {
            float a_in = 0.0f;
            if (l == 0) {
                #pragma unroll
                for (int q = 0; q < 16; ++q) {
                    float4 v = x4[q];
                    CH(a_in, v.x, wx[4*q+0]); CH(a_in, v.y, wx[4*q+1]);
                    CH(a_in, v.z, wx[4*q+2]); CH(a_in, v.w, wx[4*q+3]);
                }
            } else {
                const float4* hp = (const float4*)h_lds[l-1];
                float hv[16];
                *(float4*)&hv[0]  = hp[0]; *(float4*)&hv[4]  = hp[1];
                *(float4*)&hv[8]  = hp[2]; *(float4*)&hv[12] = hp[3];
                #pragma unroll
                for (int j = 0; j < HID; ++j) CH(a_in, hv[j], wi[l-1][j]);
            }
            float a_rec = 0.0f;
            {
                const float4* hc = (const float4*)h_lds[l];
                float hv[16];
                *(float4*)&hv[0]  = hc[0]; *(float4*)&hv[4]  = hc[1];
                *(float4*)&hv[8]  = hc[2]; *(float4*)&hv[12] = hc[3];
                #pragma unroll
                for (int j = 0; j < HID; ++j) CH(a_rec, hv[j], wr[l][j]);
            }
            const float z = bfr(bfr(a_in + a_rec) + bias[l]);
            const float a = tg ? tanh_np(z) : sig_np(z);
            const float fv = __shfl(a, (lane + 15) & 63);
            const float gv = __shfl(a, (lane + 30) & 63);
            const float ov = __shfl(a, (lane + 45) & 63);
            const float cn = bfr(bfr(fv * c[l]) + bfr(a * gv));
            c[l] = cn;
            const float hn = bfr(ov * tanh_np(cn));
            if (lane < HID) h_lds[l][lane] = hn;
            if (l == NLAY-1 && t == len-1) hout = hn;
        }
        x_lds[lane] = xn;
    }
    if (lane < HID) out[s * HID + lane] = hout;
}

extern "C" void kernel_launch(void* const* d_in, const int* in_sizes, int n_in,
                              void* d_out, int out_size, void* d_ws, size_t ws_size,
                              hipStream_t stream) {
    const float* emb     = (const float*)d_in[0];
    const int*   lengths = (const int*)  d_in[1];
    const float* Wih0    = (const float*)d_in[2];
    const float* Wihr    = (const float*)d_in[3];
    const float* Whh     = (const float*)d_in[4];
    const float* bih     = (const float*)d_in[5];
    const float* bhh     = (const float*)d_in[6];
    float* out = (float*)d_out;

    const size_t need = (size_t)BSZ * T2 * NG * sizeof(unsigned short);
    if (ws_size >= need) {
        unsigned short* pa = (unsigned short*)d_ws;
        proj0<<<2048, 256, 0, stream>>>(emb, lengths, Wih0, pa);
        lstm4_pipe<<<BSZ, 448, 0, stream>>>(lengths, pa, Wihr, Whh, bih, bhh, out);
    } else {
        lstm4_bf16np<<<BSZ, 64, 0, stream>>>(emb, lengths, Wih0, Wihr, Whh, bih, bhh, out);
    }
}

// Round 11
// 2492.649 us; speedup vs baseline: 1.0314x; 1.0314x over previous
//
#include <hip/hip_runtime.h>

#define HID 15
#define NG  60      // 4*HID
#define DIM 64
#define T2  2048
#define NLAY 4
#define BSZ 512

// bf16 RNE rounding — PROVEN bit-trick (rounds 6/7). v_cvt_pk_bf16_f32
// produced NaNs twice (even battery-guarded) — do not revisit.
__device__ __forceinline__ float bfr(float x) {
    unsigned u = __float_as_uint(x);
    u = (u + 0x7FFFu + ((u >> 16) & 1u)) & 0xFFFF0000u;
    return __uint_as_float(u);
}
// one bf16-rounded multiply-accumulate term: acc = bf(acc + bf(a*b))
#define CH(acc, a, b) acc = bfr(acc + bfr((a) * (b)))

__device__ __forceinline__ float tanh_np(float z) {
    const float e = __expf(-2.0f * z);
    return bfr((1.0f - e) / (1.0f + e));
}
__device__ __forceinline__ float sig_np(float z) {
    const float e   = bfr(__expf(-z));
    const float den = bfr(1.0f + e);
    return bfr(1.0f / den);
}

// ============ Fused kernel: 4 main (recurrence) + 4 producer waves ============
// Main wave l (0-3): R7-exact layer recurrence, t = k - l, one barrier per
//   superstep; h handoff via parity-double-buffered h_lds (R7-proven).
// Producer wave w (4-7, w'=wave-4): layer-0 projection row t=(k&~3)+4+w',
//   16 of 64 chain links per superstep (p=k&3), published to ring[t&15] at
//   p==3 (end of superstep t-w'-1, >=1 superstep before wave 0 reads it at
//   superstep t). Slot t&15 reused by row t+16 starting superstep t+8+..,
//   long after consumption. Rows 0-3 computed in the prologue.
// Numerics: per-gate op sequence identical to rounds 6/7 -> bit-identical.
__global__ __launch_bounds__(512, 1)
void lstm4_fused(const float* __restrict__ emb,
                 const int*   __restrict__ lengths,
                 const float* __restrict__ Wih0,
                 const float* __restrict__ Wihr,
                 const float* __restrict__ Whh,
                 const float* __restrict__ bih,
                 const float* __restrict__ bhh,
                 float* __restrict__ out)
{
    const int s    = blockIdx.x;
    const int wave = threadIdx.x >> 6;
    const int lane = threadIdx.x & 63;
    const int g    = (lane < NG) ? lane : (NG - 1);   // clamp idle lanes

    __shared__ __align__(16) float h_lds[2][NLAY][16];
    __shared__ __align__(16) float ring[16][64];   // a_in rows (bf16-valued f32)
    __shared__ __align__(16) float xst[4][64];     // per-producer staged x row

    int len = lengths[s];
    len = len < 1 ? 1 : (len > T2 ? T2 : len);
    const int nss = len + NLAY - 1;

    const bool tg = (lane >= 30 && lane < 45);

    if (wave < NLAY) {
        // ---------------- MAIN wave: layer l = wave (R7 body) ----------------
        const int l = wave;
        float wr[16], wi[16];
        #pragma unroll
        for (int j = 0; j < HID; ++j) wr[j] = bfr(Whh[(l*NG + g)*HID + j]);
        wr[15] = 0.0f;
        if (l > 0) {
            #pragma unroll
            for (int j = 0; j < HID; ++j) wi[j] = bfr(Wihr[((l-1)*NG + g)*HID + j]);
            wi[15] = 0.0f;
        } else {
            #pragma unroll
            for (int j = 0; j < 16; ++j) wi[j] = 0.0f;
        }
        const float bias_ = bfr(bfr(bih[l*NG + g]) + bfr(bhh[l*NG + g]));

        float c_ = 0.0f;
        float hs[HID];
        #pragma unroll
        for (int j = 0; j < HID; ++j) hs[j] = 0.0f;

        if (lane < 16) { h_lds[0][l][lane] = 0.0f; h_lds[1][l][lane] = 0.0f; }
        __syncthreads();                       // producers published rows 0-3

        for (int k = 0; k < nss; ++k) {
            const int t = k - l;
            if (t >= 0 && t < len) {           // wave-uniform predicate
                float a_in = 0.0f, a_rec = 0.0f;
                float hv[16];

                if (l == 0) {
                    a_in = ring[t & 15][g];    // produced >=1 superstep ago
                } else {                       // issue LDS reads early
                    const float4* hp = (const float4*)h_lds[t & 1][l - 1];
                    *(float4*)&hv[0]  = hp[0]; *(float4*)&hv[4]  = hp[1];
                    *(float4*)&hv[8]  = hp[2]; *(float4*)&hv[12] = hp[3];
                }

                // two independent 15-link chains -> ILP fills dep latency
                #pragma unroll
                for (int j = 0; j < HID; ++j) CH(a_rec, hs[j], wr[j]);
                if (l > 0) {
                    #pragma unroll
                    for (int j = 0; j < HID; ++j) CH(a_in, hv[j], wi[j]);
                }

                const float z = bfr(bfr(a_in + a_rec) + bias_);
                const float a = tg ? tanh_np(z) : sig_np(z);

                const float fv = __shfl(a, (lane + 15) & 63);
                const float gv = __shfl(a, (lane + 30) & 63);
                const float ov = __shfl(a, (lane + 45) & 63);

                const float cn = bfr(bfr(fv * c_) + bfr(a * gv));
                c_ = cn;
                const float hn = bfr(ov * tanh_np(cn));

                #pragma unroll
                for (int j = 0; j < HID; ++j)
                    hs[j] = __uint_as_float(__builtin_amdgcn_readlane(__float_as_uint(hn), j));

                if (lane < HID) h_lds[t & 1][l][lane] = hn;
                if (l == NLAY - 1 && t == len - 1 && lane < HID)
                    out[s * HID + lane] = hn;
            }
            __syncthreads();                   // end of superstep
        }
    } else {
        // ------------- PRODUCER wave: layer-0 projection rows -------------
        const int w = wave - NLAY;             // 0..3
        float wx[DIM];
        #pragma unroll
        for (int q = 0; q < 16; ++q) {
            float4 v = *(const float4*)(Wih0 + g*DIM + 4*q);
            wx[4*q+0] = bfr(v.x); wx[4*q+1] = bfr(v.y);
            wx[4*q+2] = bfr(v.z); wx[4*q+3] = bfr(v.w);
        }
        const float* xb = emb + (size_t)s * T2 * DIM;

        // 4 chain links with compile-time indices (no runtime reg indexing)
        #define PROJ_QUAD(Q) { \
            float4 v = xv[(Q)]; \
            CH(acc, v.x, wx[4*(Q)+0]); CH(acc, v.y, wx[4*(Q)+1]); \
            CH(acc, v.z, wx[4*(Q)+2]); CH(acc, v.w, wx[4*(Q)+3]); }

        // prologue: rows 0..3 fully
        if (w < len) {
            xst[w][lane] = bfr(xb[w * DIM + lane]);   // in-wave write->read
            const float4* xv = (const float4*)xst[w];
            float acc = 0.0f;
            PROJ_QUAD(0)  PROJ_QUAD(1)  PROJ_QUAD(2)  PROJ_QUAD(3)
            PROJ_QUAD(4)  PROJ_QUAD(5)  PROJ_QUAD(6)  PROJ_QUAD(7)
            PROJ_QUAD(8)  PROJ_QUAD(9)  PROJ_QUAD(10) PROJ_QUAD(11)
            PROJ_QUAD(12) PROJ_QUAD(13) PROJ_QUAD(14) PROJ_QUAD(15)
            ring[w][lane] = acc;
        }
        float xnext = 0.0f;
        if (4 + w < len) xnext = xb[(4 + w) * DIM + lane];  // prime pipeline
        __syncthreads();

        float acc = 0.0f;
        for (int k = 0; k < nss; ++k) {
            const int p = k & 3;
            const int t = (k & ~3) + 4 + w;    // wave-uniform
            if (t < len) {
                const float4* xv = (const float4*)xst[w];
                if (p == 0) {
                    xst[w][lane] = bfr(xnext); // row t staged (in-wave order)
                    if (t + 4 < len) xnext = xb[(size_t)(t + 4) * DIM + lane];
                    acc = 0.0f;
                }
                switch (p) {                   // 16 links, static indices
                    case 0: PROJ_QUAD(0)  PROJ_QUAD(1)  PROJ_QUAD(2)  PROJ_QUAD(3)  break;
                    case 1: PROJ_QUAD(4)  PROJ_QUAD(5)  PROJ_QUAD(6)  PROJ_QUAD(7)  break;
                    case 2: PROJ_QUAD(8)  PROJ_QUAD(9)  PROJ_QUAD(10) PROJ_QUAD(11) break;
                    default: PROJ_QUAD(12) PROJ_QUAD(13) PROJ_QUAD(14) PROJ_QUAD(15)
                             ring[t & 15][lane] = acc;  // ready for superstep t
                }
            }
            __syncthreads();                   // end of superstep
        }
        #undef PROJ_QUAD
    }
}

extern "C" void kernel_launch(void* const* d_in, const int* in_sizes, int n_in,
                              void* d_out, int out_size, void* d_ws, size_t ws_size,
                              hipStream_t stream) {
    const float* emb     = (const float*)d_in[0];
    const int*   lengths = (const int*)  d_in[1];
    const float* Wih0    = (const float*)d_in[2];
    const float* Wihr    = (const float*)d_in[3];
    const float* Whh     = (const float*)d_in[4];
    const float* bih     = (const float*)d_in[5];
    const float* bhh     = (const float*)d_in[6];
    float* out = (float*)d_out;

    const int B = out_size / HID;   // 512
    lstm4_fused<<<B, 512, 0, stream>>>(emb, lengths, Wih0, Wihr, Whh, bih, bhh, out);
}